// Round 5
// baseline (1151.300 us; speedup 1.0000x reference)
//
#include <hip/hip_runtime.h>
#include <hip/hip_fp16.h>

#define N_NODES 100000
#define N_EDGES 3200000
#define N_GRAPHS 2048
#define DIM 32
#define FEAT 78
#define OUT_DIM 128
#define BN_EPS 1e-5f

#define BSHIFT 9
#define BSIZE 512
#define NB ((N_NODES + BSIZE - 1) / BSIZE)
#define CHUNK 8192

#define NTILES (N_NODES / 16)          // 6250
#define AGG_BLOCKS ((NTILES + 3) / 4)  // 1563

typedef _Float16 f16x8 __attribute__((ext_vector_type(8)));
typedef float f32x4 __attribute__((ext_vector_type(4)));

// ---------------- K1: coarse bucket histogram ----------------
__global__ __launch_bounds__(256) void bucket_hist_kernel(const int* __restrict__ dst,
                                                          int* __restrict__ bcnt) {
    __shared__ int lh[256];
    int tid = threadIdx.x;
    lh[tid] = 0;
    __syncthreads();
    int i = blockIdx.x * blockDim.x + tid;
    int stride = gridDim.x * blockDim.x;
    for (; i < N_EDGES; i += stride)
        atomicAdd(&lh[dst[i] >> BSHIFT], 1);
    __syncthreads();
    if (tid < NB && lh[tid])
        atomicAdd(&bcnt[tid], lh[tid]);
}

// ---------------- K2: scan over buckets ----------------
__global__ __launch_bounds__(256) void bucket_scan_kernel(const int* __restrict__ bcnt,
                                                          int* __restrict__ bstart,
                                                          int* __restrict__ bcursor,
                                                          int* __restrict__ rowst) {
    __shared__ int sc[256];
    int tid = threadIdx.x;
    int v = (tid < NB) ? bcnt[tid] : 0;
    sc[tid] = v;
    __syncthreads();
    for (int off = 1; off < 256; off <<= 1) {
        int nv = (tid >= off) ? sc[tid - off] : 0;
        __syncthreads();
        sc[tid] += nv;
        __syncthreads();
    }
    if (tid < NB) {
        int ex = sc[tid] - v;
        bstart[tid] = ex;
        bcursor[tid] = ex;
    }
    if (tid == 0) {
        bstart[NB] = N_EDGES;
        rowst[N_NODES] = N_EDGES;
    }
}

// ---------------- K3: multisplit scatter into bucket segments ----------------
__global__ __launch_bounds__(256) void bucket_scatter_kernel(const int* __restrict__ src,
                                                             const int* __restrict__ dst,
                                                             int* __restrict__ bcursor,
                                                             int* __restrict__ bsrc,
                                                             unsigned short* __restrict__ blow) {
    __shared__ int lsrc[CHUNK];
    __shared__ int ldst[CHUNK];
    __shared__ int lhist[256];
    __shared__ int sc[256];
    __shared__ int lpre[256];
    __shared__ int gbase[256];
    __shared__ int lcur[256];
    int tid = threadIdx.x;
    int base = blockIdx.x * CHUNK;
    int n = N_EDGES - base; if (n > CHUNK) n = CHUNK;

    lhist[tid] = 0;
    __syncthreads();
    for (int i = tid; i < n; i += 256)
        atomicAdd(&lhist[dst[base + i] >> BSHIFT], 1);
    __syncthreads();
    int v = lhist[tid];
    sc[tid] = v;
    __syncthreads();
    for (int off = 1; off < 256; off <<= 1) {
        int nv = (tid >= off) ? sc[tid - off] : 0;
        __syncthreads();
        sc[tid] += nv;
        __syncthreads();
    }
    int ex = sc[tid] - v;
    lpre[tid] = ex;
    lcur[tid] = ex;
    if (tid < NB && v)
        gbase[tid] = atomicAdd(&bcursor[tid], v);
    __syncthreads();
    for (int i = tid; i < n; i += 256) {
        int d = dst[base + i];
        int s = src[base + i];
        int b = d >> BSHIFT;
        int pos = atomicAdd(&lcur[b], 1);
        lsrc[pos] = s;
        ldst[pos] = d;
    }
    __syncthreads();
    for (int i = tid; i < n; i += 256) {
        int d = ldst[i];
        int b = d >> BSHIFT;
        int gpos = gbase[b] + (i - lpre[b]);
        bsrc[gpos] = lsrc[i];
        blow[gpos] = (unsigned short)(d & (BSIZE - 1));
    }
}

// ---------------- K4: per-bucket counting sort -> csr + rowst ----------------
__global__ __launch_bounds__(256) void node_sort_kernel(const int* __restrict__ bstart,
                                                        const int* __restrict__ bsrc,
                                                        const unsigned short* __restrict__ blow,
                                                        int* __restrict__ csr,
                                                        int* __restrict__ rowst) {
    __shared__ int lcnt[BSIZE];
    __shared__ int sc[256];
    __shared__ int lpre[BSIZE];
    __shared__ int lcur[BSIZE];
    int tid = threadIdx.x;
    int b = blockIdx.x;
    int ss = bstart[b], se = bstart[b + 1];
    lcnt[tid] = 0; lcnt[tid + 256] = 0;
    __syncthreads();
    for (int i = ss + tid; i < se; i += 256)
        atomicAdd(&lcnt[blow[i]], 1);
    __syncthreads();
    int a0 = lcnt[2 * tid], a1 = lcnt[2 * tid + 1];
    int s = a0 + a1;
    sc[tid] = s;
    __syncthreads();
    for (int off = 1; off < 256; off <<= 1) {
        int nv = (tid >= off) ? sc[tid - off] : 0;
        __syncthreads();
        sc[tid] += nv;
        __syncthreads();
    }
    int ex = sc[tid] - s;
    lpre[2 * tid] = ex;
    lpre[2 * tid + 1] = ex + a0;
    lcur[2 * tid] = ex;
    lcur[2 * tid + 1] = ex + a0;
    __syncthreads();
    int node_base = b << BSHIFT;
    for (int j = tid; j < BSIZE; j += 256) {
        int node = node_base + j;
        if (node < N_NODES) rowst[node] = ss + lpre[j];
    }
    for (int i = ss + tid; i < se; i += 256) {
        int nloc = blow[i];
        int pos = atomicAdd(&lcur[nloc], 1);
        csr[ss + pos] = bsrc[i];
    }
}

// ---------------- t16 = fp16(x @ W1a)  (78 -> 32) ----------------
__global__ __launch_bounds__(256) void transform1_kernel(const float* __restrict__ x,
                                                         const float* __restrict__ W,
                                                         __half* __restrict__ t) {
    __shared__ float Wl[FEAT * DIM];
    for (int i = threadIdx.x; i < FEAT * DIM; i += blockDim.x) Wl[i] = W[i];
    __syncthreads();
    int lane = threadIdx.x & 31;
    int group = threadIdx.x >> 5;
    int gpb = blockDim.x >> 5;
    for (int node = blockIdx.x * gpb + group; node < N_NODES; node += gridDim.x * gpb) {
        const float* xr = x + (size_t)node * FEAT;
        float r0 = xr[lane];
        float r1 = xr[32 + lane];
        float r2 = (lane < FEAT - 64) ? xr[64 + lane] : 0.f;
        float acc = 0.f;
        #pragma unroll
        for (int k = 0; k < 32; ++k)
            acc += __shfl(r0, k, 32) * Wl[k * DIM + lane];
        #pragma unroll
        for (int k = 0; k < 32; ++k)
            acc += __shfl(r1, k, 32) * Wl[(32 + k) * DIM + lane];
        #pragma unroll
        for (int k = 0; k < FEAT - 64; ++k)
            acc += __shfl(r2, k, 32) * Wl[(64 + k) * DIM + lane];
        t[((size_t)node << 5) + lane] = __float2half(acc);
    }
}

// ---------------- prep: fold BN into next layer's Wa ----------------
__global__ __launch_bounds__(1024) void prep_kernel(const float* __restrict__ stats,
                                                    const float* __restrict__ gamma,
                                                    const float* __restrict__ beta,
                                                    const float* __restrict__ Wa,
                                                    float* __restrict__ Wp) {
    __shared__ float a[DIM], c[DIM];
    int tid = threadIdx.x;
    if (tid < DIM) {
        float mu = stats[tid] * (1.f / N_NODES);
        float var = stats[DIM + tid] * (1.f / N_NODES) - mu * mu;
        float av = gamma[tid] * rsqrtf(var + BN_EPS);
        a[tid] = av;
        c[tid] = beta[tid] - mu * av;
    }
    __syncthreads();
    int k = tid >> 5;
    Wp[tid] = a[k] * Wa[tid];
    if (tid < DIM) {
        float s = 0.f;
        for (int kk = 0; kk < DIM; ++kk)
            s += c[kk] * Wa[kk * DIM + tid];
        Wp[DIM * DIM + tid] = s;
    }
}

__global__ __launch_bounds__(1024) void prep_id_kernel(float* __restrict__ Wp) {
    int tid = threadIdx.x;
    Wp[tid] = ((tid >> 5) == (tid & 31)) ? 1.f : 0.f;
    if (tid < DIM) Wp[DIM * DIM + tid] = 0.f;
}

#define ACC8(v) do { const __half2* hp_ = (const __half2*)&(v); float2 f_; \
  f_ = __half22float2(hp_[0]); a0 += f_.x; a1 += f_.y; \
  f_ = __half22float2(hp_[1]); a2 += f_.x; a3 += f_.y; \
  f_ = __half22float2(hp_[2]); a4 += f_.x; a5 += f_.y; \
  f_ = __half22float2(hp_[3]); a6 += f_.x; a7 += f_.y; } while (0)

// ---------------- agg: shuffle-free gather + MFMA MLP ----------------
// Gather: lane l -> node g=(l&63)>>2 of its wave's 16-node tile, 16B chunk q=l&3.
// MLP: 16x16x32 f16 MFMA, A = agg tile (LDS), B = BN-folded weights (regs).
__global__ __launch_bounds__(256) void agg_kernel(const __half* __restrict__ hin,
                                                  const int* __restrict__ rowst,
                                                  const int* __restrict__ csr,
                                                  const float* __restrict__ Wp,
                                                  const float* __restrict__ bias_a,
                                                  const float* __restrict__ Wb,
                                                  const float* __restrict__ bias_b,
                                                  __half* __restrict__ hout,
                                                  float* __restrict__ stats) {
    __shared__ __align__(16) _Float16 Hl[4][512];
    __shared__ __align__(16) _Float16 H2[4][512];
    __shared__ __align__(16) _Float16 Fl[4][512];
    __shared__ __align__(16) float dg[4][16];
    int tid = threadIdx.x;
    int wave = tid >> 6;
    int l = tid & 63;
    int d0 = l & 15, kg = l >> 4;

    // B-fragments: lane l holds B[k = kg*8+e][col], col = d0 (tile0) / d0+16 (tile1)
    f16x8 bA0, bA1, bB0, bB1;
    #pragma unroll
    for (int e = 0; e < 8; ++e) {
        int k = kg * 8 + e;
        bA0[e] = (_Float16)Wp[k * 32 + d0];
        bA1[e] = (_Float16)Wp[k * 32 + d0 + 16];
        bB0[e] = (_Float16)Wb[k * 32 + d0];
        bB1[e] = (_Float16)Wb[k * 32 + d0 + 16];
    }
    float cw0 = Wp[DIM * DIM + d0], cw1 = Wp[DIM * DIM + d0 + 16];
    float ba0 = bias_a[d0], ba1 = bias_a[d0 + 16];
    float bb0 = bias_b[d0], bb1 = bias_b[d0 + 16];

    int tile = blockIdx.x * 4 + wave;
    bool active = tile < NTILES;
    int g = l >> 2, q = l & 3;
    int node = tile * 16 + g;

    if (active) {
        int rs = rowst[node], re = rowst[node + 1];
        float a0 = 0.f, a1 = 0.f, a2 = 0.f, a3 = 0.f,
              a4 = 0.f, a5 = 0.f, a6 = 0.f, a7 = 0.f;
        // self row
        uint4 vs = *(const uint4*)(hin + ((size_t)node << 5) + (q << 3));
        ACC8(vs);
        int p = rs;
        for (; p + 2 <= re; p += 2) {
            int s0 = csr[p], s1 = csr[p + 1];
            uint4 v0 = *(const uint4*)(hin + ((size_t)s0 << 5) + (q << 3));
            uint4 v1 = *(const uint4*)(hin + ((size_t)s1 << 5) + (q << 3));
            ACC8(v0);
            ACC8(v1);
        }
        if (p < re) {
            uint4 v0 = *(const uint4*)(hin + ((size_t)csr[p] << 5) + (q << 3));
            ACC8(v0);
        }
        f16x8 hv;
        hv[0] = (_Float16)a0; hv[1] = (_Float16)a1;
        hv[2] = (_Float16)a2; hv[3] = (_Float16)a3;
        hv[4] = (_Float16)a4; hv[5] = (_Float16)a5;
        hv[6] = (_Float16)a6; hv[7] = (_Float16)a7;
        *(f16x8*)&Hl[wave][g * 32 + q * 8] = hv;
        if (q == 0) dg[wave][g] = (float)(re - rs + 1);
    }
    __syncthreads();

    if (active) {
        f16x8 af = *(f16x8*)&Hl[wave][d0 * 32 + kg * 8];
        f32x4 c0 = {ba0, ba0, ba0, ba0};
        f32x4 c1 = {ba1, ba1, ba1, ba1};
        c0 = __builtin_amdgcn_mfma_f32_16x16x32_f16(af, bA0, c0, 0, 0, 0);
        c1 = __builtin_amdgcn_mfma_f32_16x16x32_f16(af, bA1, c1, 0, 0, 0);
        f32x4 degv = *(f32x4*)&dg[wave][kg * 4];
        #pragma unroll
        for (int rr = 0; rr < 4; ++rr) {
            float v0 = fmaxf(c0[rr] + degv[rr] * cw0, 0.f);
            float v1 = fmaxf(c1[rr] + degv[rr] * cw1, 0.f);
            int row = kg * 4 + rr;
            H2[wave][row * 32 + d0] = (_Float16)v0;
            H2[wave][row * 32 + d0 + 16] = (_Float16)v1;
        }
    }
    __syncthreads();

    float s0 = 0.f, ss0 = 0.f, s1 = 0.f, ss1 = 0.f;
    if (active) {
        f16x8 a2f = *(f16x8*)&H2[wave][d0 * 32 + kg * 8];
        f32x4 c0 = {bb0, bb0, bb0, bb0};
        f32x4 c1 = {bb1, bb1, bb1, bb1};
        c0 = __builtin_amdgcn_mfma_f32_16x16x32_f16(a2f, bB0, c0, 0, 0, 0);
        c1 = __builtin_amdgcn_mfma_f32_16x16x32_f16(a2f, bB1, c1, 0, 0, 0);
        #pragma unroll
        for (int rr = 0; rr < 4; ++rr) {
            float y0 = fmaxf(c0[rr], 0.f);
            float y1 = fmaxf(c1[rr], 0.f);
            s0 += y0; ss0 += y0 * y0;
            s1 += y1; ss1 += y1 * y1;
            int row = kg * 4 + rr;
            Fl[wave][row * 32 + d0] = (_Float16)y0;
            Fl[wave][row * 32 + d0 + 16] = (_Float16)y1;
        }
    }
    __syncthreads();

    if (active) {
        uint4 v = *(uint4*)&Fl[wave][g * 32 + q * 8];
        *(uint4*)(hout + ((size_t)node << 5) + (q << 3)) = v;
        // BN stats: reduce over lane bits 4,5 (nodes), lanes kg==0 commit
        s0 += __shfl_xor(s0, 16); s0 += __shfl_xor(s0, 32);
        ss0 += __shfl_xor(ss0, 16); ss0 += __shfl_xor(ss0, 32);
        s1 += __shfl_xor(s1, 16); s1 += __shfl_xor(s1, 32);
        ss1 += __shfl_xor(ss1, 16); ss1 += __shfl_xor(ss1, 32);
        if (kg == 0) {
            atomicAdd(&stats[d0], s0);
            atomicAdd(&stats[DIM + d0], ss0);
            atomicAdd(&stats[d0 + 16], s1);
            atomicAdd(&stats[DIM + d0 + 16], ss1);
        }
    }
}

// ---------------- final BN + global_add_pool (run-length, batch sorted) ----------------
#define POOL_BLOCKS 512
__global__ __launch_bounds__(256) void bn_pool_kernel(const __half* __restrict__ h,
                                                      const float* __restrict__ stats,
                                                      const float* __restrict__ gamma,
                                                      const float* __restrict__ beta,
                                                      const int* __restrict__ batch,
                                                      float* __restrict__ pooled) {
    int lane = threadIdx.x & 31;
    int group = threadIdx.x >> 5;
    float mu = stats[lane] * (1.f / N_NODES);
    float var = stats[DIM + lane] * (1.f / N_NODES) - mu * mu;
    float inv = rsqrtf(var + BN_EPS);
    float a = gamma[lane] * inv;
    float c = beta[lane] - mu * a;
    const int ngroups = POOL_BLOCKS * 8;
    const int chunk = (N_NODES + ngroups - 1) / ngroups;
    int g = blockIdx.x * 8 + group;
    int start = g * chunk;
    if (start >= N_NODES) return;
    int end = start + chunk; if (end > N_NODES) end = N_NODES;
    int cur = batch[start];
    float s = 0.f;
    for (int node = start; node < end; ++node) {
        float v = __half2float(h[((size_t)node << 5) + lane]) * a + c;
        int bg = batch[node];
        if (bg != cur) {
            atomicAdd(&pooled[cur * DIM + lane], s);
            s = 0.f;
            cur = bg;
        }
        s += v;
    }
    atomicAdd(&pooled[cur * DIM + lane], s);
}

// ---------------- out = relu(pooled @ Wfc + bfc) ----------------
__global__ __launch_bounds__(256) void fc_kernel(const float* __restrict__ pooled,
                                                 const float* __restrict__ Wfc,
                                                 const float* __restrict__ bfc,
                                                 float* __restrict__ out) {
    __shared__ float Wl[DIM * OUT_DIM];
    for (int i = threadIdx.x; i < DIM * OUT_DIM; i += blockDim.x) Wl[i] = Wfc[i];
    __syncthreads();
    int idx = blockIdx.x * blockDim.x + threadIdx.x;
    int stride = gridDim.x * blockDim.x;
    for (; idx < N_GRAPHS * OUT_DIM; idx += stride) {
        int g = idx >> 7;
        int o = idx & 127;
        float acc = bfc[o];
        #pragma unroll
        for (int k = 0; k < DIM; ++k)
            acc += pooled[g * DIM + k] * Wl[k * OUT_DIM + o];
        out[idx] = fmaxf(acc, 0.f);
    }
}

extern "C" void kernel_launch(void* const* d_in, const int* in_sizes, int n_in,
                              void* d_out, int out_size, void* d_ws, size_t ws_size,
                              hipStream_t stream) {
    const float* x   = (const float*)d_in[0];
    const int* eidx  = (const int*)d_in[1];
    const int* src   = eidx;
    const int* dst   = eidx + N_EDGES;
    const int* batch = (const int*)d_in[2];
    const float* W1a = (const float*)d_in[3];
    const float* b1a = (const float*)d_in[4];
    const float* W1b = (const float*)d_in[5];
    const float* b1b = (const float*)d_in[6];
    const float* Wa  = (const float*)d_in[7];
    const float* ba  = (const float*)d_in[8];
    const float* Wb  = (const float*)d_in[9];
    const float* bb  = (const float*)d_in[10];
    const float* gamma = (const float*)d_in[11];
    const float* beta  = (const float*)d_in[12];
    const float* Wfc = (const float*)d_in[13];
    const float* bfc = (const float*)d_in[14];
    float* out = (float*)d_out;

    __half* t16 = (__half*)d_ws;                           // 3.2M halfs
    __half* h_a = t16 + (size_t)N_NODES * DIM;             // 3.2M halfs
    __half* h_b = h_a + (size_t)N_NODES * DIM;             // 3.2M halfs
    float* stats  = (float*)(h_b + (size_t)N_NODES * DIM); // 5*64
    float* pooled = stats + 5 * 64;                        // 65536
    float* Wp     = pooled + N_GRAPHS * DIM;               // 5 * 1056
    int* csr      = (int*)(Wp + 5 * 1056);                 // 3.2M
    int* rowst    = csr + N_EDGES;                         // N_NODES+1
    int* bcnt     = rowst + N_NODES + 1;                   // 256
    int* bstart   = bcnt + 256;                            // NB+1
    int* bcursor  = bstart + NB + 1;                       // 256

    int* bsrc            = (int*)t16;             // CSR-build scratch aliases
    unsigned short* blow = (unsigned short*)h_b;

    hipMemsetAsync(bcnt, 0, 256 * sizeof(int), stream);
    hipMemsetAsync(stats, 0, 5 * 64 * sizeof(float), stream);
    hipMemsetAsync(pooled, 0, N_GRAPHS * DIM * sizeof(float), stream);

    bucket_hist_kernel<<<1024, 256, 0, stream>>>(dst, bcnt);
    bucket_scan_kernel<<<1, 256, 0, stream>>>(bcnt, bstart, bcursor, rowst);
    bucket_scatter_kernel<<<(N_EDGES + CHUNK - 1) / CHUNK, 256, 0, stream>>>(src, dst, bcursor, bsrc, blow);
    node_sort_kernel<<<NB, 256, 0, stream>>>(bstart, bsrc, blow, csr, rowst);

    transform1_kernel<<<2048, 256, 0, stream>>>(x, W1a, t16);

    prep_id_kernel<<<1, 1024, 0, stream>>>(Wp);
    agg_kernel<<<AGG_BLOCKS, 256, 0, stream>>>(t16, rowst, csr, Wp, b1a, W1b, b1b, h_a, stats + 0);

    const __half* hin = h_a;
    __half* hout = h_b;
    for (int i = 0; i < 4; ++i) {
        float* Wpi = Wp + (i + 1) * 1056;
        prep_kernel<<<1, 1024, 0, stream>>>(stats + i * 64, gamma + i * DIM, beta + i * DIM,
                                            Wa + i * DIM * DIM, Wpi);
        agg_kernel<<<AGG_BLOCKS, 256, 0, stream>>>(hin, rowst, csr, Wpi, ba + i * DIM,
                                                   Wb + i * DIM * DIM, bb + i * DIM,
                                                   hout, stats + (i + 1) * 64);
        __half* tmp = (__half*)hin; hin = hout; hout = tmp;
    }
    bn_pool_kernel<<<POOL_BLOCKS, 256, 0, stream>>>(h_a, stats + 4 * 64,
                                                    gamma + 4 * DIM, beta + 4 * DIM, batch, pooled);
    fc_kernel<<<1024, 256, 0, stream>>>(pooled, Wfc, bfc, out);
}

// Round 6
// 1080.434 us; speedup vs baseline: 1.0656x; 1.0656x over previous
//
#include <hip/hip_runtime.h>
#include <hip/hip_fp16.h>

#define N_NODES 100000
#define N_EDGES 3200000
#define N_GRAPHS 2048
#define DIM 32
#define FEAT 78
#define OUT_DIM 128
#define BN_EPS 1e-5f

#define BSHIFT 9
#define BSIZE 512
#define NB ((N_NODES + BSIZE - 1) / BSIZE)
#define CHUNK 8192

#define NTILES (N_NODES / 16)          // 6250
#define AGG_BLOCKS ((NTILES + 3) / 4)  // 1563

typedef _Float16 f16x8 __attribute__((ext_vector_type(8)));
typedef float f32x4 __attribute__((ext_vector_type(4)));

// ---------------- K1: coarse bucket histogram ----------------
__global__ __launch_bounds__(256) void bucket_hist_kernel(const int* __restrict__ dst,
                                                          int* __restrict__ bcnt) {
    __shared__ int lh[256];
    int tid = threadIdx.x;
    lh[tid] = 0;
    __syncthreads();
    int i = blockIdx.x * blockDim.x + tid;
    int stride = gridDim.x * blockDim.x;
    for (; i < N_EDGES; i += stride)
        atomicAdd(&lh[dst[i] >> BSHIFT], 1);
    __syncthreads();
    if (tid < NB && lh[tid])
        atomicAdd(&bcnt[tid], lh[tid]);
}

// ---------------- K2: scan over buckets ----------------
__global__ __launch_bounds__(256) void bucket_scan_kernel(const int* __restrict__ bcnt,
                                                          int* __restrict__ bstart,
                                                          int* __restrict__ bcursor,
                                                          int* __restrict__ rowst) {
    __shared__ int sc[256];
    int tid = threadIdx.x;
    int v = (tid < NB) ? bcnt[tid] : 0;
    sc[tid] = v;
    __syncthreads();
    for (int off = 1; off < 256; off <<= 1) {
        int nv = (tid >= off) ? sc[tid - off] : 0;
        __syncthreads();
        sc[tid] += nv;
        __syncthreads();
    }
    if (tid < NB) {
        int ex = sc[tid] - v;
        bstart[tid] = ex;
        bcursor[tid] = ex;
    }
    if (tid == 0) {
        bstart[NB] = N_EDGES;
        rowst[N_NODES] = N_EDGES;
    }
}

// ---------------- K3: multisplit scatter into bucket segments ----------------
__global__ __launch_bounds__(256) void bucket_scatter_kernel(const int* __restrict__ src,
                                                             const int* __restrict__ dst,
                                                             int* __restrict__ bcursor,
                                                             int* __restrict__ bsrc,
                                                             unsigned short* __restrict__ blow) {
    __shared__ int lsrc[CHUNK];
    __shared__ int ldst[CHUNK];
    __shared__ int lhist[256];
    __shared__ int sc[256];
    __shared__ int lpre[256];
    __shared__ int gbase[256];
    __shared__ int lcur[256];
    int tid = threadIdx.x;
    int base = blockIdx.x * CHUNK;
    int n = N_EDGES - base; if (n > CHUNK) n = CHUNK;

    lhist[tid] = 0;
    __syncthreads();
    for (int i = tid; i < n; i += 256)
        atomicAdd(&lhist[dst[base + i] >> BSHIFT], 1);
    __syncthreads();
    int v = lhist[tid];
    sc[tid] = v;
    __syncthreads();
    for (int off = 1; off < 256; off <<= 1) {
        int nv = (tid >= off) ? sc[tid - off] : 0;
        __syncthreads();
        sc[tid] += nv;
        __syncthreads();
    }
    int ex = sc[tid] - v;
    lpre[tid] = ex;
    lcur[tid] = ex;
    if (tid < NB && v)
        gbase[tid] = atomicAdd(&bcursor[tid], v);
    __syncthreads();
    for (int i = tid; i < n; i += 256) {
        int d = dst[base + i];
        int s = src[base + i];
        int b = d >> BSHIFT;
        int pos = atomicAdd(&lcur[b], 1);
        lsrc[pos] = s;
        ldst[pos] = d;
    }
    __syncthreads();
    for (int i = tid; i < n; i += 256) {
        int d = ldst[i];
        int b = d >> BSHIFT;
        int gpos = gbase[b] + (i - lpre[b]);
        bsrc[gpos] = lsrc[i];
        blow[gpos] = (unsigned short)(d & (BSIZE - 1));
    }
}

// ---------------- K4: per-bucket counting sort -> csr + rowst ----------------
__global__ __launch_bounds__(256) void node_sort_kernel(const int* __restrict__ bstart,
                                                        const int* __restrict__ bsrc,
                                                        const unsigned short* __restrict__ blow,
                                                        int* __restrict__ csr,
                                                        int* __restrict__ rowst) {
    __shared__ int lcnt[BSIZE];
    __shared__ int sc[256];
    __shared__ int lpre[BSIZE];
    __shared__ int lcur[BSIZE];
    int tid = threadIdx.x;
    int b = blockIdx.x;
    int ss = bstart[b], se = bstart[b + 1];
    lcnt[tid] = 0; lcnt[tid + 256] = 0;
    __syncthreads();
    for (int i = ss + tid; i < se; i += 256)
        atomicAdd(&lcnt[blow[i]], 1);
    __syncthreads();
    int a0 = lcnt[2 * tid], a1 = lcnt[2 * tid + 1];
    int s = a0 + a1;
    sc[tid] = s;
    __syncthreads();
    for (int off = 1; off < 256; off <<= 1) {
        int nv = (tid >= off) ? sc[tid - off] : 0;
        __syncthreads();
        sc[tid] += nv;
        __syncthreads();
    }
    int ex = sc[tid] - s;
    lpre[2 * tid] = ex;
    lpre[2 * tid + 1] = ex + a0;
    lcur[2 * tid] = ex;
    lcur[2 * tid + 1] = ex + a0;
    __syncthreads();
    int node_base = b << BSHIFT;
    for (int j = tid; j < BSIZE; j += 256) {
        int node = node_base + j;
        if (node < N_NODES) rowst[node] = ss + lpre[j];
    }
    for (int i = ss + tid; i < se; i += 256) {
        int nloc = blow[i];
        int pos = atomicAdd(&lcur[nloc], 1);
        csr[ss + pos] = bsrc[i];
    }
}

// ---------------- t16 = fp16(x @ W1a)  (78 -> 32) ----------------
__global__ __launch_bounds__(256) void transform1_kernel(const float* __restrict__ x,
                                                         const float* __restrict__ W,
                                                         __half* __restrict__ t) {
    __shared__ float Wl[FEAT * DIM];
    for (int i = threadIdx.x; i < FEAT * DIM; i += blockDim.x) Wl[i] = W[i];
    __syncthreads();
    int lane = threadIdx.x & 31;
    int group = threadIdx.x >> 5;
    int gpb = blockDim.x >> 5;
    for (int node = blockIdx.x * gpb + group; node < N_NODES; node += gridDim.x * gpb) {
        const float* xr = x + (size_t)node * FEAT;
        float r0 = xr[lane];
        float r1 = xr[32 + lane];
        float r2 = (lane < FEAT - 64) ? xr[64 + lane] : 0.f;
        float acc = 0.f;
        #pragma unroll
        for (int k = 0; k < 32; ++k)
            acc += __shfl(r0, k, 32) * Wl[k * DIM + lane];
        #pragma unroll
        for (int k = 0; k < 32; ++k)
            acc += __shfl(r1, k, 32) * Wl[(32 + k) * DIM + lane];
        #pragma unroll
        for (int k = 0; k < FEAT - 64; ++k)
            acc += __shfl(r2, k, 32) * Wl[(64 + k) * DIM + lane];
        t[((size_t)node << 5) + lane] = __float2half(acc);
    }
}

// ---------------- prep: fold BN into next layer's Wa ----------------
__global__ __launch_bounds__(1024) void prep_kernel(const float* __restrict__ stats,
                                                    const float* __restrict__ gamma,
                                                    const float* __restrict__ beta,
                                                    const float* __restrict__ Wa,
                                                    float* __restrict__ Wp) {
    __shared__ float a[DIM], c[DIM];
    int tid = threadIdx.x;
    if (tid < DIM) {
        float mu = stats[tid] * (1.f / N_NODES);
        float var = stats[DIM + tid] * (1.f / N_NODES) - mu * mu;
        float av = gamma[tid] * rsqrtf(var + BN_EPS);
        a[tid] = av;
        c[tid] = beta[tid] - mu * av;
    }
    __syncthreads();
    int k = tid >> 5;
    Wp[tid] = a[k] * Wa[tid];
    if (tid < DIM) {
        float s = 0.f;
        for (int kk = 0; kk < DIM; ++kk)
            s += c[kk] * Wa[kk * DIM + tid];
        Wp[DIM * DIM + tid] = s;
    }
}

__global__ __launch_bounds__(1024) void prep_id_kernel(float* __restrict__ Wp) {
    int tid = threadIdx.x;
    Wp[tid] = ((tid >> 5) == (tid & 31)) ? 1.f : 0.f;
    if (tid < DIM) Wp[DIM * DIM + tid] = 0.f;
}

#define ACC8(v) do { const __half2* hp_ = (const __half2*)&(v); float2 f_; \
  f_ = __half22float2(hp_[0]); a0 += f_.x; a1 += f_.y; \
  f_ = __half22float2(hp_[1]); a2 += f_.x; a3 += f_.y; \
  f_ = __half22float2(hp_[2]); a4 += f_.x; a5 += f_.y; \
  f_ = __half22float2(hp_[3]); a6 += f_.x; a7 += f_.y; } while (0)

// ---------------- agg: deep-MLP gather + MFMA MLP, no block barriers ----------------
// Lane l: node g=(l>>2) of the wave's 16-node tile, 16B chunk q=l&3.
// Gather: 8 uint4 row-loads in flight per lane; tail is one predicated 8-wide round.
// All LDS is wave-private; waves run fully decoupled.
__global__ __launch_bounds__(256) void agg_kernel(const __half* __restrict__ hin,
                                                  const int* __restrict__ rowst,
                                                  const int* __restrict__ csr,
                                                  const float* __restrict__ Wp,
                                                  const float* __restrict__ bias_a,
                                                  const float* __restrict__ Wb,
                                                  const float* __restrict__ bias_b,
                                                  __half* __restrict__ hout,
                                                  float* __restrict__ stats) {
    __shared__ __align__(16) _Float16 Hl[4][512];
    __shared__ __align__(16) _Float16 H2[4][512];
    __shared__ __align__(16) _Float16 Fl[4][512];
    __shared__ __align__(16) float dg[4][16];
    int tid = threadIdx.x;
    int wave = tid >> 6;
    int l = tid & 63;
    int d0 = l & 15, kg = l >> 4;
    int g = l >> 2, q = l & 3;

    int tile = blockIdx.x * 4 + wave;
    if (tile >= NTILES) return;
    int node = tile * 16 + g;

    // ---- gather phase ----
    {
        int rs = rowst[node], re = rowst[node + 1];
        float a0 = 0.f, a1 = 0.f, a2 = 0.f, a3 = 0.f,
              a4 = 0.f, a5 = 0.f, a6 = 0.f, a7 = 0.f;
        uint4 vs = *(const uint4*)(hin + ((size_t)node << 5) + (q << 3));
        ACC8(vs);
        int p = rs;
        for (; p + 8 <= re; p += 8) {
            int s[8];
            #pragma unroll
            for (int j = 0; j < 8; ++j) s[j] = csr[p + j];
            uint4 v[8];
            #pragma unroll
            for (int j = 0; j < 8; ++j)
                v[j] = *(const uint4*)(hin + ((size_t)s[j] << 5) + (q << 3));
            #pragma unroll
            for (int j = 0; j < 8; ++j) ACC8(v[j]);
        }
        if (p < re) {
            uint4 v[8];
            #pragma unroll
            for (int j = 0; j < 8; ++j) {
                uint4 vv = {0, 0, 0, 0};
                if (p + j < re)
                    vv = *(const uint4*)(hin + ((size_t)csr[p + j] << 5) + (q << 3));
                v[j] = vv;
            }
            #pragma unroll
            for (int j = 0; j < 8; ++j) ACC8(v[j]);
        }
        f16x8 hv;
        hv[0] = (_Float16)a0; hv[1] = (_Float16)a1;
        hv[2] = (_Float16)a2; hv[3] = (_Float16)a3;
        hv[4] = (_Float16)a4; hv[5] = (_Float16)a5;
        hv[6] = (_Float16)a6; hv[7] = (_Float16)a7;
        *(f16x8*)&Hl[wave][g * 32 + q * 8] = hv;
        if (q == 0) dg[wave][g] = (float)(re - rs + 1);
    }
    asm volatile("s_waitcnt lgkmcnt(0)" ::: "memory");

    // ---- B fragments (loaded after gather to ease register pressure) ----
    f16x8 bA0, bA1, bB0, bB1;
    #pragma unroll
    for (int e = 0; e < 8; ++e) {
        int k = kg * 8 + e;
        bA0[e] = (_Float16)Wp[k * 32 + d0];
        bA1[e] = (_Float16)Wp[k * 32 + d0 + 16];
        bB0[e] = (_Float16)Wb[k * 32 + d0];
        bB1[e] = (_Float16)Wb[k * 32 + d0 + 16];
    }
    float cw0 = Wp[DIM * DIM + d0], cw1 = Wp[DIM * DIM + d0 + 16];
    float ba0 = bias_a[d0], ba1 = bias_a[d0 + 16];
    float bb0 = bias_b[d0], bb1 = bias_b[d0 + 16];

    // ---- MLP layer A ----
    {
        f16x8 af = *(f16x8*)&Hl[wave][d0 * 32 + kg * 8];
        f32x4 c0 = {ba0, ba0, ba0, ba0};
        f32x4 c1 = {ba1, ba1, ba1, ba1};
        c0 = __builtin_amdgcn_mfma_f32_16x16x32_f16(af, bA0, c0, 0, 0, 0);
        c1 = __builtin_amdgcn_mfma_f32_16x16x32_f16(af, bA1, c1, 0, 0, 0);
        f32x4 degv = *(f32x4*)&dg[wave][kg * 4];
        #pragma unroll
        for (int rr = 0; rr < 4; ++rr) {
            float v0 = fmaxf(c0[rr] + degv[rr] * cw0, 0.f);
            float v1 = fmaxf(c1[rr] + degv[rr] * cw1, 0.f);
            int row = kg * 4 + rr;
            H2[wave][row * 32 + d0] = (_Float16)v0;
            H2[wave][row * 32 + d0 + 16] = (_Float16)v1;
        }
    }
    asm volatile("s_waitcnt lgkmcnt(0)" ::: "memory");

    // ---- MLP layer B + BN stats ----
    float s0 = 0.f, ss0 = 0.f, s1 = 0.f, ss1 = 0.f;
    {
        f16x8 a2f = *(f16x8*)&H2[wave][d0 * 32 + kg * 8];
        f32x4 c0 = {bb0, bb0, bb0, bb0};
        f32x4 c1 = {bb1, bb1, bb1, bb1};
        c0 = __builtin_amdgcn_mfma_f32_16x16x32_f16(a2f, bB0, c0, 0, 0, 0);
        c1 = __builtin_amdgcn_mfma_f32_16x16x32_f16(a2f, bB1, c1, 0, 0, 0);
        #pragma unroll
        for (int rr = 0; rr < 4; ++rr) {
            float y0 = fmaxf(c0[rr], 0.f);
            float y1 = fmaxf(c1[rr], 0.f);
            s0 += y0; ss0 += y0 * y0;
            s1 += y1; ss1 += y1 * y1;
            int row = kg * 4 + rr;
            Fl[wave][row * 32 + d0] = (_Float16)y0;
            Fl[wave][row * 32 + d0 + 16] = (_Float16)y1;
        }
    }
    asm volatile("s_waitcnt lgkmcnt(0)" ::: "memory");

    // ---- store + stats ----
    {
        uint4 v = *(uint4*)&Fl[wave][g * 32 + q * 8];
        *(uint4*)(hout + ((size_t)node << 5) + (q << 3)) = v;
        s0 += __shfl_xor(s0, 16); s0 += __shfl_xor(s0, 32);
        ss0 += __shfl_xor(ss0, 16); ss0 += __shfl_xor(ss0, 32);
        s1 += __shfl_xor(s1, 16); s1 += __shfl_xor(s1, 32);
        ss1 += __shfl_xor(ss1, 16); ss1 += __shfl_xor(ss1, 32);
        if (kg == 0) {
            atomicAdd(&stats[d0], s0);
            atomicAdd(&stats[DIM + d0], ss0);
            atomicAdd(&stats[d0 + 16], s1);
            atomicAdd(&stats[DIM + d0 + 16], ss1);
        }
    }
}

// ---------------- final BN + global_add_pool (run-length, batch sorted) ----------------
#define POOL_BLOCKS 512
__global__ __launch_bounds__(256) void bn_pool_kernel(const __half* __restrict__ h,
                                                      const float* __restrict__ stats,
                                                      const float* __restrict__ gamma,
                                                      const float* __restrict__ beta,
                                                      const int* __restrict__ batch,
                                                      float* __restrict__ pooled) {
    int lane = threadIdx.x & 31;
    int group = threadIdx.x >> 5;
    float mu = stats[lane] * (1.f / N_NODES);
    float var = stats[DIM + lane] * (1.f / N_NODES) - mu * mu;
    float inv = rsqrtf(var + BN_EPS);
    float a = gamma[lane] * inv;
    float c = beta[lane] - mu * a;
    const int ngroups = POOL_BLOCKS * 8;
    const int chunk = (N_NODES + ngroups - 1) / ngroups;
    int g = blockIdx.x * 8 + group;
    int start = g * chunk;
    if (start >= N_NODES) return;
    int end = start + chunk; if (end > N_NODES) end = N_NODES;
    int cur = batch[start];
    float s = 0.f;
    for (int node = start; node < end; ++node) {
        float v = __half2float(h[((size_t)node << 5) + lane]) * a + c;
        int bg = batch[node];
        if (bg != cur) {
            atomicAdd(&pooled[cur * DIM + lane], s);
            s = 0.f;
            cur = bg;
        }
        s += v;
    }
    atomicAdd(&pooled[cur * DIM + lane], s);
}

// ---------------- out = relu(pooled @ Wfc + bfc) ----------------
__global__ __launch_bounds__(256) void fc_kernel(const float* __restrict__ pooled,
                                                 const float* __restrict__ Wfc,
                                                 const float* __restrict__ bfc,
                                                 float* __restrict__ out) {
    __shared__ float Wl[DIM * OUT_DIM];
    for (int i = threadIdx.x; i < DIM * OUT_DIM; i += blockDim.x) Wl[i] = Wfc[i];
    __syncthreads();
    int idx = blockIdx.x * blockDim.x + threadIdx.x;
    int stride = gridDim.x * blockDim.x;
    for (; idx < N_GRAPHS * OUT_DIM; idx += stride) {
        int g = idx >> 7;
        int o = idx & 127;
        float acc = bfc[o];
        #pragma unroll
        for (int k = 0; k < DIM; ++k)
            acc += pooled[g * DIM + k] * Wl[k * OUT_DIM + o];
        out[idx] = fmaxf(acc, 0.f);
    }
}

extern "C" void kernel_launch(void* const* d_in, const int* in_sizes, int n_in,
                              void* d_out, int out_size, void* d_ws, size_t ws_size,
                              hipStream_t stream) {
    const float* x   = (const float*)d_in[0];
    const int* eidx  = (const int*)d_in[1];
    const int* src   = eidx;
    const int* dst   = eidx + N_EDGES;
    const int* batch = (const int*)d_in[2];
    const float* W1a = (const float*)d_in[3];
    const float* b1a = (const float*)d_in[4];
    const float* W1b = (const float*)d_in[5];
    const float* b1b = (const float*)d_in[6];
    const float* Wa  = (const float*)d_in[7];
    const float* ba  = (const float*)d_in[8];
    const float* Wb  = (const float*)d_in[9];
    const float* bb  = (const float*)d_in[10];
    const float* gamma = (const float*)d_in[11];
    const float* beta  = (const float*)d_in[12];
    const float* Wfc = (const float*)d_in[13];
    const float* bfc = (const float*)d_in[14];
    float* out = (float*)d_out;

    __half* t16 = (__half*)d_ws;                           // 3.2M halfs
    __half* h_a = t16 + (size_t)N_NODES * DIM;             // 3.2M halfs
    __half* h_b = h_a + (size_t)N_NODES * DIM;             // 3.2M halfs
    float* stats  = (float*)(h_b + (size_t)N_NODES * DIM); // 5*64
    float* pooled = stats + 5 * 64;                        // 65536
    float* Wp     = pooled + N_GRAPHS * DIM;               // 5 * 1056
    int* csr      = (int*)(Wp + 5 * 1056);                 // 3.2M
    int* rowst    = csr + N_EDGES;                         // N_NODES+1
    int* bcnt     = rowst + N_NODES + 1;                   // 256
    int* bstart   = bcnt + 256;                            // NB+1
    int* bcursor  = bstart + NB + 1;                       // 256

    int* bsrc            = (int*)t16;             // CSR-build scratch aliases
    unsigned short* blow = (unsigned short*)h_b;

    hipMemsetAsync(bcnt, 0, 256 * sizeof(int), stream);
    hipMemsetAsync(stats, 0, 5 * 64 * sizeof(float), stream);
    hipMemsetAsync(pooled, 0, N_GRAPHS * DIM * sizeof(float), stream);

    bucket_hist_kernel<<<1024, 256, 0, stream>>>(dst, bcnt);
    bucket_scan_kernel<<<1, 256, 0, stream>>>(bcnt, bstart, bcursor, rowst);
    bucket_scatter_kernel<<<(N_EDGES + CHUNK - 1) / CHUNK, 256, 0, stream>>>(src, dst, bcursor, bsrc, blow);
    node_sort_kernel<<<NB, 256, 0, stream>>>(bstart, bsrc, blow, csr, rowst);

    transform1_kernel<<<2048, 256, 0, stream>>>(x, W1a, t16);

    prep_id_kernel<<<1, 1024, 0, stream>>>(Wp);
    agg_kernel<<<AGG_BLOCKS, 256, 0, stream>>>(t16, rowst, csr, Wp, b1a, W1b, b1b, h_a, stats + 0);

    const __half* hin = h_a;
    __half* hout = h_b;
    for (int i = 0; i < 4; ++i) {
        float* Wpi = Wp + (i + 1) * 1056;
        prep_kernel<<<1, 1024, 0, stream>>>(stats + i * 64, gamma + i * DIM, beta + i * DIM,
                                            Wa + i * DIM * DIM, Wpi);
        agg_kernel<<<AGG_BLOCKS, 256, 0, stream>>>(hin, rowst, csr, Wpi, ba + i * DIM,
                                                   Wb + i * DIM * DIM, bb + i * DIM,
                                                   hout, stats + (i + 1) * 64);
        __half* tmp = (__half*)hin; hin = hout; hout = tmp;
    }
    bn_pool_kernel<<<POOL_BLOCKS, 256, 0, stream>>>(h_a, stats + 4 * 64,
                                                    gamma + 4 * DIM, beta + 4 * DIM, batch, pooled);
    fc_kernel<<<1024, 256, 0, stream>>>(pooled, Wfc, bfc, out);
}